// Round 15
// baseline (556.933 us; speedup 1.0000x reference)
//
#include <hip/hip_runtime.h>
#include <math.h>

constexpr int N    = 100000;
constexpr int E    = 1600000;
constexpr int DIN  = 256;
constexpr int D    = 128;
constexpr int L    = 4;
constexpr float EPS = 1e-5f;
constexpr int NBIN = 64;      // node-range bins for 2-pass CSR build
constexpr int BINW = 1563;    // ceil(N / NBIN)
constexpr int SLOT = 32768;   // slack staging slots per bin (expected ~25000)

constexpr int F0B   = 782;    // f0-role blocks (N/128)
constexpr int CBB   = 782;    // countbin-role blocks (E/2048)
constexpr int PREPB = 64;     // wbc-prep role blocks

typedef __attribute__((ext_vector_type(8))) short bf16x8;
typedef __attribute__((ext_vector_type(4))) float f32x4;
typedef __attribute__((ext_vector_type(2))) float f32x2;

__device__ inline ushort f2b(float f) {
    uint u = __float_as_uint(f);
    uint r = u + 0x7fffu + ((u >> 16) & 1u);
    return (ushort)(r >> 16);
}
__device__ inline float b2f(ushort b) { return __uint_as_float(((uint)b) << 16); }

// ---------------- fused: f0 GEMM | edge bin | wbc prep (role-split blocks) ----------------

__global__ __launch_bounds__(512, 2) void k_f0_countbin(
        const float* __restrict__ x, const float* __restrict__ lin1_w,
        const float* __restrict__ bias, ushort* __restrict__ f_bf,
        ushort* __restrict__ x0_bf,
        const int* __restrict__ row, const int* __restrict__ col,
        int* __restrict__ bfill, int2* __restrict__ stag,
        const float* __restrict__ w1, const float* __restrict__ w2, float4 betas,
        ushort* __restrict__ wbc) {
    __shared__ uint4 Bl[4096];   // 64 KB (f0 role); first 512B reused by bin role
    int t = threadIdx.x;

    if (blockIdx.x >= F0B + CBB) {
        // ---- role 2: wbc prep (beta*w + (1-beta)I, bf16, [col][k] layout) ----
        int base = (blockIdx.x - (F0B + CBB)) * 2048 + t * 4;
        #pragma unroll
        for (int j = 0; j < 4; j++) {
            int i = base + j;
            if (i < L * D * 256) {
                int l = i >> 15, r = i & 32767, d = r >> 8, k = r & 255;
                float beta = (l == 0) ? betas.x : (l == 1) ? betas.y
                           : (l == 2) ? betas.z : betas.w;
                float v;
                if (k < 128) v = beta * w1[l * 16384 + k * 128 + d] + ((k == d) ? (1.f - beta) : 0.f);
                else { int kk = k - 128; v = beta * w2[l * 16384 + kk * 128 + d] + ((kk == d) ? (1.f - beta) : 0.f); }
                wbc[l * 32768 + d * 256 + k] = f2b(v);
            }
        }
        return;
    }

    int role = blockIdx.x & 1, rid = blockIdx.x >> 1;

    if (role == 1) {
        // ---- bin: slack-bin staging only (counts recovered later per-bin, no cnt atomics) ----
        int* hist = (int*)Bl;
        int* base = hist + NBIN;
        if (t < NBIN) hist[t] = 0;
        __syncthreads();
        int e0 = rid * 2048 + t * 4;
        bool val = (e0 < E);   // E%4==0 -> all-or-nothing
        int r[4], c[4], li[4];
        if (val) {
            *(int4*)&c[0] = *(const int4*)(col + e0);
            *(int4*)&r[0] = *(const int4*)(row + e0);
            #pragma unroll
            for (int j = 0; j < 4; j++)
                li[j] = atomicAdd(&hist[c[j] / BINW], 1);
        }
        __syncthreads();
        if (t < NBIN) base[t] = hist[t] ? atomicAdd(&bfill[t], hist[t]) : 0;
        __syncthreads();
        if (val) {
            #pragma unroll
            for (int j = 0; j < 4; j++) {
                int b = c[j] / BINW;
                stag[(size_t)b * SLOT + base[b] + li[j]] = make_int2(r[j], c[j]);
            }
        }
        return;
    }

    // ---- f0 GEMM: B staged from lin1_w (fp32 -> bf16 in-flight) ----
    #pragma unroll
    for (int it = 0; it < 8; it++) {
        int d = it * 512 + t, c = d >> 5, ck = d & 31;
        const float4* src = (const float4*)(lin1_w + c * 256 + ck * 8);
        float4 lo = src[0], hi = src[1];
        uint4 p;
        p.x = (uint)f2b(lo.x) | ((uint)f2b(lo.y) << 16);
        p.y = (uint)f2b(lo.z) | ((uint)f2b(lo.w) << 16);
        p.z = (uint)f2b(hi.x) | ((uint)f2b(hi.y) << 16);
        p.w = (uint)f2b(hi.z) | ((uint)f2b(hi.w) << 16);
        Bl[c * 32 + (ck ^ (c & 7))] = p;
    }
    __syncthreads();

    int wv = t >> 6, lane = t & 63;
    int l16 = lane & 15, g16 = lane >> 4;
    int row0 = (rid * 8 + wv) * 16;
    if (row0 >= N) return;

    const uint4* xb = (const uint4*)(x + (size_t)(row0 + l16) * 256);
    uint4 xr[16];
    #pragma unroll
    for (int ks = 0; ks < 8; ks++) {
        xr[2 * ks]     = xb[ks * 8 + g16 * 2];
        xr[2 * ks + 1] = xb[ks * 8 + g16 * 2 + 1];
    }

    f32x4 acc[8];
    #pragma unroll
    for (int n = 0; n < 8; n++) acc[n] = f32x4{0.f, 0.f, 0.f, 0.f};

    #pragma unroll
    for (int ks = 0; ks < 8; ks++) {
        float4 lo = *(const float4*)&xr[2 * ks];
        float4 hi = *(const float4*)&xr[2 * ks + 1];
        uint4 p;
        p.x = (uint)f2b(lo.x) | ((uint)f2b(lo.y) << 16);
        p.y = (uint)f2b(lo.z) | ((uint)f2b(lo.w) << 16);
        p.z = (uint)f2b(hi.x) | ((uint)f2b(hi.y) << 16);
        p.w = (uint)f2b(hi.z) | ((uint)f2b(hi.w) << 16);
        bf16x8 a = *(bf16x8*)&p;
        int xo = (ks * 4 + g16) ^ (l16 & 7);
        const char* bp = (const char*)Bl + l16 * 512 + xo * 16;
        #pragma unroll
        for (int n = 0; n < 8; n++) {
            bf16x8 b = *(const bf16x8*)(bp + n * 8192);
            acc[n] = __builtin_amdgcn_mfma_f32_16x16x32_bf16(a, b, acc[n], 0, 0, 0);
        }
    }

    float bc[8];
    #pragma unroll
    for (int n = 0; n < 8; n++) bc[n] = bias[n * 16 + l16];
    #pragma unroll
    for (int j = 0; j < 4; j++) {
        int gr = row0 + g16 * 4 + j;
        #pragma unroll
        for (int n = 0; n < 8; n++) {
            float r = fmaxf(acc[n][j] + bc[n], 0.f);
            size_t o = (size_t)gr * 128 + n * 16 + l16;
            f_bf[o] = f2b(r);
            x0_bf[o] = f2b(0.5f * r);
        }
    }
}

// ---------------- per-bin degree count (LDS histogram, zero global atomics) ----------------

__global__ __launch_bounds__(256) void k_bincount(const int2* __restrict__ stag,
        const int* __restrict__ bfill, int* __restrict__ cnt) {
    __shared__ int lc[BINW];
    int b = blockIdx.x, t = threadIdx.x;
    for (int i = t; i < BINW; i += 256) lc[i] = 0;
    __syncthreads();
    int n = bfill[b];
    const int2* sb = stag + (size_t)b * SLOT;
    for (int i = t; i < n; i += 256)
        atomicAdd(&lc[sb[i].y - b * BINW], 1);
    __syncthreads();
    int n0 = b * BINW;
    for (int i = t; i < BINW; i += 256)
        if (n0 + i < N) cnt[n0 + i] = lc[i];
}

// ---------------- CSR finish ----------------

__global__ void k_sumdis(const int* __restrict__ cnt, int* __restrict__ bsum,
                         float* __restrict__ dis) {
    __shared__ int s[256];
    int base = blockIdx.x * 1024;
    int t = threadIdx.x;
    int a = 0;
    for (int j = 0; j < 4; j++) {
        int idx = base + t * 4 + j;
        if (idx < N) {
            int cv = cnt[idx];
            a += cv;
            dis[idx] = rsqrtf((float)cv + 1.0f);
        }
    }
    s[t] = a; __syncthreads();
    for (int off = 128; off > 0; off >>= 1) {
        if (t < off) s[t] += s[t + off];
        __syncthreads();
    }
    if (t == 0) bsum[blockIdx.x] = s[0];
}

__global__ void k_scan(int* __restrict__ bsum, int nb) {
    __shared__ int s[128];
    int t = threadIdx.x;
    int v = (t < nb) ? bsum[t] : 0;
    s[t] = v; __syncthreads();
    for (int off = 1; off < 128; off <<= 1) {
        int x = (t >= off) ? s[t - off] : 0;
        __syncthreads();
        s[t] += x;
        __syncthreads();
    }
    if (t < nb) bsum[t] = s[t] - v;   // exclusive
}

__global__ void k_offsets(const int* __restrict__ cnt, const int* __restrict__ bsum,
                          int* __restrict__ offs, int* __restrict__ cur) {
    __shared__ int ls[256];
    int b = blockIdx.x, t = threadIdx.x;
    int base = b * 1024;
    int v[4]; int s = 0;
    for (int j = 0; j < 4; j++) {
        int idx = base + t * 4 + j;
        v[j] = (idx < N) ? cnt[idx] : 0;
        s += v[j];
    }
    ls[t] = s; __syncthreads();
    for (int off = 1; off < 256; off <<= 1) {
        int x = (t >= off) ? ls[t - off] : 0;
        __syncthreads();
        ls[t] += x;
        __syncthreads();
    }
    int excl = ((t == 0) ? 0 : ls[t - 1]) + bsum[b];
    for (int j = 0; j < 4; j++) {
        int idx = base + t * 4 + j;
        if (idx < N) { offs[idx] = excl; cur[idx] = excl; }
        excl += v[j];
        if (idx == N - 1) offs[N] = excl;
    }
}

// pass 2: scatter within bin. 16 XCD-aligned parts per bin (b, b+64, ... same XCD).
__global__ __launch_bounds__(256) void k_unbin(const int2* __restrict__ stag,
        const int* __restrict__ bfill, const float* __restrict__ dis,
        int* __restrict__ cur, int2* __restrict__ csr) {
    int b = blockIdx.x & (NBIN - 1);
    int part = blockIdx.x >> 6;          // 0..15
    int n = bfill[b];
    const int2* sbase = stag + (size_t)b * SLOT;
    for (int i = part * 256 + threadIdx.x; i < n; i += 4096) {
        int2 rc = sbase[i];
        float v = dis[rc.x] * dis[rc.y];
        int pos = atomicAdd(&cur[rc.y], 1);
        csr[pos] = make_int2(rc.x, __float_as_int(v));
    }
}

// ---------------- combine GEMM (round-8 verified) ----------------

__global__ __launch_bounds__(512, 2) void k_combine_mfma(const ushort* __restrict__ g_bf,
        const ushort* __restrict__ x0_bf, const ushort* __restrict__ wb,
        ushort* __restrict__ h_bf, float* __restrict__ sr) {
    __shared__ uint4 Bl[4096];   // 64 KB
    __shared__ float red1[512];
    __shared__ float red2[512];
    int t = threadIdx.x;
    #pragma unroll
    for (int it = 0; it < 8; it++) {
        int d = it * 512 + t, c = d >> 5, ck = d & 31;
        Bl[c * 32 + (ck ^ (c & 7))] = ((const uint4*)wb)[d];
    }
    __syncthreads();

    int wv = t >> 6, lane = t & 63;
    int l16 = lane & 15, g16 = lane >> 4;
    int row0 = (blockIdx.x * 8 + wv) * 16;
    bool active = row0 < N;

    f32x4 acc[8];
    #pragma unroll
    for (int n = 0; n < 8; n++) acc[n] = f32x4{0.f, 0.f, 0.f, 0.f};

    if (active) {
        const uint4* ga = (const uint4*)(g_bf  + (size_t)(row0 + l16) * 128);
        const uint4* xa = (const uint4*)(x0_bf + (size_t)(row0 + l16) * 128);
        uint4 ar[8];
        #pragma unroll
        for (int ks = 0; ks < 4; ks++) ar[ks]     = ga[ks * 4 + g16];
        #pragma unroll
        for (int ks = 0; ks < 4; ks++) ar[ks + 4] = xa[ks * 4 + g16];

        #pragma unroll
        for (int ks = 0; ks < 8; ks++) {
            bf16x8 a = *(bf16x8*)&ar[ks];
            int xo = (ks * 4 + g16) ^ (l16 & 7);
            const char* bp = (const char*)Bl + l16 * 512 + xo * 16;
            #pragma unroll
            for (int n = 0; n < 8; n++) {
                bf16x8 b = *(const bf16x8*)(bp + n * 8192);
                acc[n] = __builtin_amdgcn_mfma_f32_16x16x32_bf16(a, b, acc[n], 0, 0, 0);
            }
        }
    }

    float sum = 0.f, sq = 0.f;
    if (active) {
        #pragma unroll
        for (int n = 0; n < 8; n++)
            #pragma unroll
            for (int j = 0; j < 4; j++) { float v = acc[n][j]; sum += v; sq += v * v; }
        #pragma unroll
        for (int j = 0; j < 4; j++) {
            int gr = row0 + g16 * 4 + j;
            #pragma unroll
            for (int n = 0; n < 8; n++)
                h_bf[(size_t)gr * 128 + n * 16 + l16] = f2b(acc[n][j]);
        }
    }

    red1[t] = sum; red2[t] = sq; __syncthreads();
    for (int off = 256; off > 0; off >>= 1) {
        if (t < off) { red1[t] += red1[t + off]; red2[t] += red2[t + off]; }
        __syncthreads();
    }
    if (t == 0) { atomicAdd(&sr[0], red1[0]); atomicAdd(&sr[1], red2[0]); }
}

// ---------------- aggregation (verified floor) ----------------

template <int AFFINE>
__global__ __launch_bounds__(256) void k_agg(const ushort* __restrict__ src,
        const int* __restrict__ offs, const int2* __restrict__ csr,
        const float* __restrict__ dis, const float* __restrict__ sr,
        const float* __restrict__ nw, const float* __restrict__ nb,
        ushort* __restrict__ g_bf) {
    int node = blockIdx.x * 4 + (threadIdx.x >> 6);
    if (node >= N) return;
    int lane = threadIdx.x & 63;
    int q = lane >> 4, cl = lane & 15;       // lane owns channels [cl*8, cl*8+8)
    const uint4* fu = (const uint4*)src;     // row = 16 uint4

    f32x2 sc[4], sh[4];
    if constexpr (AFFINE) {
        const float inv_n = 1.0f / ((float)N * (float)D);
        float m = sr[0] * inv_n;
        float var = fmaxf(sr[1] * inv_n - m * m, 0.f);
        float inv = 1.0f / (sqrtf(var) + EPS);
        #pragma unroll
        for (int p = 0; p < 4; p++) {
            float w0 = nw[cl * 8 + 2 * p], w1 = nw[cl * 8 + 2 * p + 1];
            sc[p] = f32x2{inv * w0, inv * w1};
            sh[p] = f32x2{nb[cl * 8 + 2 * p]     - m * inv * w0,
                          nb[cl * 8 + 2 * p + 1] - m * inv * w1};
        }
    }

    f32x2 a2[4];
    #pragma unroll
    for (int p = 0; p < 4; p++) a2[p] = f32x2{0.f, 0.f};

    auto acc8 = [&](float val, uint4 rv) {
        uint uu[4] = {rv.x, rv.y, rv.z, rv.w};
        f32x2 v2 = {val, val};
        #pragma unroll
        for (int p = 0; p < 4; p++) {
            f32x2 c;
            c.x = __uint_as_float(uu[p] << 16);
            c.y = __uint_as_float(uu[p] & 0xffff0000u);
            if constexpr (AFFINE) {
                c = __builtin_elementwise_fma(c, sc[p], sh[p]);
                c = __builtin_elementwise_max(c, f32x2{0.f, 0.f});
            }
            a2[p] = __builtin_elementwise_fma(v2, c, a2[p]);
        }
    };

    float dv = dis[node];
    acc8((q == 0) ? dv * dv : 0.f, fu[(size_t)node * 16 + cl]);   // self loop

    int end = offs[node + 1];
    int i = offs[node] + q * 4;              // group q: quad {i..i+3}, stride 16
    if (i < end) {
        int2 rA[4], rB[4];
        uint4 wA[4];
        #pragma unroll
        for (int s = 0; s < 4; s++) rA[s] = csr[min(i + s, end - 1)];
        #pragma unroll
        for (int s = 0; s < 4; s++) wA[s] = fu[(size_t)rA[s].x * 16 + cl];
        #pragma unroll
        for (int s = 0; s < 4; s++) rB[s] = csr[min(i + 16 + s, end - 1)];
        while (i + 16 < end) {
            uint4 wB[4];
            #pragma unroll
            for (int s = 0; s < 4; s++) wB[s] = fu[(size_t)rB[s].x * 16 + cl];
            int2 rC[4];
            #pragma unroll
            for (int s = 0; s < 4; s++) rC[s] = csr[min(i + 32 + s, end - 1)];
            #pragma unroll
            for (int s = 0; s < 4; s++) acc8(__int_as_float(rA[s].y), wA[s]);
            #pragma unroll
            for (int s = 0; s < 4; s++) { rA[s] = rB[s]; wA[s] = wB[s]; rB[s] = rC[s]; }
            i += 16;
        }
        #pragma unroll
        for (int s = 0; s < 4; s++) {
            float v = (i + s < end) ? __int_as_float(rA[s].y) : 0.f;
            acc8(v, wA[s]);
        }
    }

    #pragma unroll
    for (int p = 0; p < 4; p++) {
        a2[p].x += __shfl_xor(a2[p].x, 16, 64);
        a2[p].x += __shfl_xor(a2[p].x, 32, 64);
        a2[p].y += __shfl_xor(a2[p].y, 16, 64);
        a2[p].y += __shfl_xor(a2[p].y, 32, 64);
    }
    if (q == 0) {
        uint4 o;
        o.x = (uint)f2b(0.5f * a2[0].x) | ((uint)f2b(0.5f * a2[0].y) << 16);
        o.y = (uint)f2b(0.5f * a2[1].x) | ((uint)f2b(0.5f * a2[1].y) << 16);
        o.z = (uint)f2b(0.5f * a2[2].x) | ((uint)f2b(0.5f * a2[2].y) << 16);
        o.w = (uint)f2b(0.5f * a2[3].x) | ((uint)f2b(0.5f * a2[3].y) << 16);
        ((uint4*)g_bf)[(size_t)node * 16 + cl] = o;
    }
}

// ---------------- final LN + relu -> fp32 out ----------------

__global__ void k_ln_final(const ushort* __restrict__ ob, const float* __restrict__ sr,
                           const float* __restrict__ nw, const float* __restrict__ nb,
                           float* __restrict__ fout) {
    int i = blockIdx.x * 256 + threadIdx.x;   // uint4 index: 8 bf16
    if (i >= N * 16) return;
    const float inv_n = 1.0f / ((float)N * (float)D);
    float m = sr[0] * inv_n;
    float var = fmaxf(sr[1] * inv_n - m * m, 0.f);
    float inv = 1.0f / (sqrtf(var) + EPS);
    uint4 v = ((const uint4*)ob)[i];
    int c = (i & 15) * 8;
    uint vv[4] = {v.x, v.y, v.z, v.w};
    float r[8];
    #pragma unroll
    for (int qd = 0; qd < 4; qd++) {
        float lo = b2f((ushort)(vv[qd] & 0xffff));
        float hi = b2f((ushort)(vv[qd] >> 16));
        r[2 * qd]     = fmaxf((lo - m) * inv * nw[c + 2 * qd]     + nb[c + 2 * qd], 0.f);
        r[2 * qd + 1] = fmaxf((hi - m) * inv * nw[c + 2 * qd + 1] + nb[c + 2 * qd + 1], 0.f);
    }
    float4 o0 = {r[0], r[1], r[2], r[3]};
    float4 o1 = {r[4], r[5], r[6], r[7]};
    ((float4*)fout)[2 * i] = o0;
    ((float4*)fout)[2 * i + 1] = o1;
}

// ---------------- launcher ----------------

extern "C" void kernel_launch(void* const* d_in, const int* in_sizes, int n_in,
                              void* d_out, int out_size, void* d_ws, size_t ws_size,
                              hipStream_t stream) {
    const float* x      = (const float*)d_in[0];
    const int*   ei     = (const int*)d_in[1];
    const float* lin1_w = (const float*)d_in[2];
    const float* lin1_b = (const float*)d_in[3];
    const float* w1     = (const float*)d_in[4];
    const float* w2     = (const float*)d_in[5];
    const float* nw     = (const float*)d_in[6];
    const float* nb     = (const float*)d_in[7];
    const int* row = ei;
    const int* col = ei + E;
    float* fout = (float*)d_out;

    char* ws = (char*)d_ws;
    size_t off0 = 0;
    auto alloc = [&](size_t bytes) -> char* {
        char* p = ws + off0;
        off0 = (off0 + bytes + 255) & ~(size_t)255;
        return p;
    };
    ushort* f_bf    = (ushort*)alloc((size_t)N * D * 2);   // f0 (post-relu, layer-0 gather src)
    ushort* x0_bf   = (ushort*)alloc((size_t)N * D * 2);   // 0.5*f0
    ushort* g_bf    = (ushort*)alloc((size_t)N * D * 2);   // agg output
    ushort* h_bf    = (ushort*)alloc((size_t)N * D * 2);   // combine output (pre-LN)
    float*  dis     = (float*) alloc((size_t)N * 4);
    int*    cnt     = (int*)   alloc((size_t)N * 4);       // fully overwritten by bincount
    // zero-initialized block: bfill | stats (single small memset)
    char*   zblk    = alloc((size_t)NBIN * 4 + 64);
    int*    bfill   = (int*)zblk;
    float*  stats   = (float*)(zblk + NBIN * 4);
    int*    offs    = (int*)   alloc((size_t)(N + 1) * 4);
    int*    cur     = (int*)   alloc((size_t)N * 4);
    int*    bsum    = (int*)   alloc((size_t)128 * 4);
    int2*   stag    = (int2*)  alloc((size_t)NBIN * SLOT * 8);
    int2*   csr     = (int2*)  alloc((size_t)E * 8);
    ushort* wbc     = (ushort*)alloc((size_t)L * D * 256 * 2);

    hipMemsetAsync(zblk, 0, (size_t)NBIN * 4 + 64, stream);

    float4 betas;
    betas.x = logf(1.0f / 1.0f + 1.0f);
    betas.y = logf(1.0f / 2.0f + 1.0f);
    betas.z = logf(1.0f / 3.0f + 1.0f);
    betas.w = logf(1.0f / 4.0f + 1.0f);

    // fused: f0 GEMM (even blocks) | edge bin (odd blocks) | wbc prep (tail)
    k_f0_countbin<<<F0B + CBB + PREPB, 512, 0, stream>>>(
        x, lin1_w, lin1_b, f_bf, x0_bf, row, col, bfill, stag,
        w1, w2, betas, wbc);

    // CSR finish: per-bin count -> sum+dis -> scan -> offsets(+cur) -> unbin
    k_bincount<<<NBIN, 256, 0, stream>>>(stag, bfill, cnt);
    int nbk = (N + 1023) / 1024;   // 98
    k_sumdis<<<nbk, 256, 0, stream>>>(cnt, bsum, dis);
    k_scan<<<1, 128, 0, stream>>>(bsum, nbk);
    k_offsets<<<nbk, 256, 0, stream>>>(cnt, bsum, offs, cur);
    k_unbin<<<NBIN * 16, 256, 0, stream>>>(stag, bfill, dis, cur, csr);

    int GB = (N / 16 + 7) / 8;   // 782
    int AGB = (N + 3) / 4;
    for (int i = 0; i < L; i++) {
        if (i == 0)
            k_agg<0><<<AGB, 256, 0, stream>>>(f_bf, offs, csr, dis, nullptr, nw, nb, g_bf);
        else
            k_agg<1><<<AGB, 256, 0, stream>>>(h_bf, offs, csr, dis, stats + 2 * (i - 1),
                                              nw, nb, g_bf);
        k_combine_mfma<<<GB, 512, 0, stream>>>(g_bf, x0_bf, wbc + (size_t)i * D * 256,
                                               h_bf, stats + 2 * i);
    }
    k_ln_final<<<(N * 16 + 255) / 256, 256, 0, stream>>>(h_bf, stats + 6, nw, nb, fout);
}

// Round 16
// 529.008 us; speedup vs baseline: 1.0528x; 1.0528x over previous
//
#include <hip/hip_runtime.h>
#include <math.h>

constexpr int N    = 100000;
constexpr int E    = 1600000;
constexpr int DIN  = 256;
constexpr int D    = 128;
constexpr int L    = 4;
constexpr float EPS = 1e-5f;
constexpr int NBIN = 256;     // node-range bins for 2-pass CSR build
constexpr int BINW = 391;     // ceil(N / NBIN)
constexpr int SLOT = 8192;    // slack staging slots per bin (expected ~6250)

constexpr int F0B   = 782;    // f0-role blocks (N/128)
constexpr int CBB   = 782;    // countbin-role blocks (E/2048)
constexpr int PREPB = 64;     // wbc-prep role blocks

typedef __attribute__((ext_vector_type(8))) short bf16x8;
typedef __attribute__((ext_vector_type(4))) float f32x4;
typedef __attribute__((ext_vector_type(2))) float f32x2;

__device__ inline ushort f2b(float f) {
    uint u = __float_as_uint(f);
    uint r = u + 0x7fffu + ((u >> 16) & 1u);
    return (ushort)(r >> 16);
}
__device__ inline float b2f(ushort b) { return __uint_as_float(((uint)b) << 16); }

// ---------------- fused: f0 GEMM | edge count+bin | wbc prep (role-split blocks) ----------------

__global__ __launch_bounds__(512, 2) void k_f0_countbin(
        const float* __restrict__ x, const float* __restrict__ lin1_w,
        const float* __restrict__ bias, ushort* __restrict__ f_bf,
        ushort* __restrict__ x0_bf,
        const int* __restrict__ row, const int* __restrict__ col,
        int* __restrict__ cnt, int* __restrict__ bfill, int2* __restrict__ stag,
        const float* __restrict__ w1, const float* __restrict__ w2, float4 betas,
        ushort* __restrict__ wbc) {
    __shared__ uint4 Bl[4096];   // 64 KB (f0 role); first 2KB reused by countbin role
    int t = threadIdx.x;

    if (blockIdx.x >= F0B + CBB) {
        // ---- role 2: wbc prep (beta*w + (1-beta)I, bf16, [col][k] layout) ----
        int base = (blockIdx.x - (F0B + CBB)) * 2048 + t * 4;
        #pragma unroll
        for (int j = 0; j < 4; j++) {
            int i = base + j;
            if (i < L * D * 256) {
                int l = i >> 15, r = i & 32767, d = r >> 8, k = r & 255;
                float beta = (l == 0) ? betas.x : (l == 1) ? betas.y
                           : (l == 2) ? betas.z : betas.w;
                float v;
                if (k < 128) v = beta * w1[l * 16384 + k * 128 + d] + ((k == d) ? (1.f - beta) : 0.f);
                else { int kk = k - 128; v = beta * w2[l * 16384 + kk * 128 + d] + ((kk == d) ? (1.f - beta) : 0.f); }
                wbc[l * 32768 + d * 256 + k] = f2b(v);
            }
        }
        return;
    }

    int role = blockIdx.x & 1, rid = blockIdx.x >> 1;

    if (role == 1) {
        // ---- countbin: per-target count + slack-bin staging ----
        // cnt atomics are latency-bound but hide under co-resident f0 MFMA waves
        // (round-15 A/B: moving them to a separate serial kernel cost +27 us).
        int* hist = (int*)Bl;
        int* base = hist + NBIN;
        if (t < NBIN) hist[t] = 0;
        __syncthreads();
        int e0 = rid * 2048 + t * 4;
        bool val = (e0 < E);   // E%4==0 -> all-or-nothing
        int r[4], c[4], li[4];
        if (val) {
            *(int4*)&c[0] = *(const int4*)(col + e0);
            *(int4*)&r[0] = *(const int4*)(row + e0);
            #pragma unroll
            for (int j = 0; j < 4; j++) {
                atomicAdd(&cnt[c[j]], 1);
                li[j] = atomicAdd(&hist[c[j] / BINW], 1);
            }
        }
        __syncthreads();
        if (t < NBIN) base[t] = hist[t] ? atomicAdd(&bfill[t], hist[t]) : 0;
        __syncthreads();
        if (val) {
            #pragma unroll
            for (int j = 0; j < 4; j++) {
                int b = c[j] / BINW;
                stag[(size_t)b * SLOT + base[b] + li[j]] = make_int2(r[j], c[j]);
            }
        }
        return;
    }

    // ---- f0 GEMM: B staged from lin1_w (fp32 -> bf16 in-flight) ----
    #pragma unroll
    for (int it = 0; it < 8; it++) {
        int d = it * 512 + t, c = d >> 5, ck = d & 31;
        const float4* src = (const float4*)(lin1_w + c * 256 + ck * 8);
        float4 lo = src[0], hi = src[1];
        uint4 p;
        p.x = (uint)f2b(lo.x) | ((uint)f2b(lo.y) << 16);
        p.y = (uint)f2b(lo.z) | ((uint)f2b(lo.w) << 16);
        p.z = (uint)f2b(hi.x) | ((uint)f2b(hi.y) << 16);
        p.w = (uint)f2b(hi.z) | ((uint)f2b(hi.w) << 16);
        Bl[c * 32 + (ck ^ (c & 7))] = p;
    }
    __syncthreads();

    int wv = t >> 6, lane = t & 63;
    int l16 = lane & 15, g16 = lane >> 4;
    int row0 = (rid * 8 + wv) * 16;
    if (row0 >= N) return;

    const uint4* xb = (const uint4*)(x + (size_t)(row0 + l16) * 256);
    uint4 xr[16];
    #pragma unroll
    for (int ks = 0; ks < 8; ks++) {
        xr[2 * ks]     = xb[ks * 8 + g16 * 2];
        xr[2 * ks + 1] = xb[ks * 8 + g16 * 2 + 1];
    }

    f32x4 acc[8];
    #pragma unroll
    for (int n = 0; n < 8; n++) acc[n] = f32x4{0.f, 0.f, 0.f, 0.f};

    #pragma unroll
    for (int ks = 0; ks < 8; ks++) {
        float4 lo = *(const float4*)&xr[2 * ks];
        float4 hi = *(const float4*)&xr[2 * ks + 1];
        uint4 p;
        p.x = (uint)f2b(lo.x) | ((uint)f2b(lo.y) << 16);
        p.y = (uint)f2b(lo.z) | ((uint)f2b(lo.w) << 16);
        p.z = (uint)f2b(hi.x) | ((uint)f2b(hi.y) << 16);
        p.w = (uint)f2b(hi.z) | ((uint)f2b(hi.w) << 16);
        bf16x8 a = *(bf16x8*)&p;
        int xo = (ks * 4 + g16) ^ (l16 & 7);
        const char* bp = (const char*)Bl + l16 * 512 + xo * 16;
        #pragma unroll
        for (int n = 0; n < 8; n++) {
            bf16x8 b = *(const bf16x8*)(bp + n * 8192);
            acc[n] = __builtin_amdgcn_mfma_f32_16x16x32_bf16(a, b, acc[n], 0, 0, 0);
        }
    }

    float bc[8];
    #pragma unroll
    for (int n = 0; n < 8; n++) bc[n] = bias[n * 16 + l16];
    #pragma unroll
    for (int j = 0; j < 4; j++) {
        int gr = row0 + g16 * 4 + j;
        #pragma unroll
        for (int n = 0; n < 8; n++) {
            float r = fmaxf(acc[n][j] + bc[n], 0.f);
            size_t o = (size_t)gr * 128 + n * 16 + l16;
            f_bf[o] = f2b(r);
            x0_bf[o] = f2b(0.5f * r);
        }
    }
}

// ---------------- CSR finish ----------------

__global__ void k_sumdis(const int* __restrict__ cnt, int* __restrict__ bsum,
                         float* __restrict__ dis) {
    __shared__ int s[256];
    int base = blockIdx.x * 1024;
    int t = threadIdx.x;
    int a = 0;
    for (int j = 0; j < 4; j++) {
        int idx = base + t * 4 + j;
        if (idx < N) {
            int cv = cnt[idx];
            a += cv;
            dis[idx] = rsqrtf((float)cv + 1.0f);
        }
    }
    s[t] = a; __syncthreads();
    for (int off = 128; off > 0; off >>= 1) {
        if (t < off) s[t] += s[t + off];
        __syncthreads();
    }
    if (t == 0) bsum[blockIdx.x] = s[0];
}

__global__ void k_scan(int* __restrict__ bsum, int nb) {
    __shared__ int s[128];
    int t = threadIdx.x;
    int v = (t < nb) ? bsum[t] : 0;
    s[t] = v; __syncthreads();
    for (int off = 1; off < 128; off <<= 1) {
        int x = (t >= off) ? s[t - off] : 0;
        __syncthreads();
        s[t] += x;
        __syncthreads();
    }
    if (t < nb) bsum[t] = s[t] - v;   // exclusive
}

__global__ void k_offsets(const int* __restrict__ cnt, const int* __restrict__ bsum,
                          int* __restrict__ offs, int* __restrict__ cur) {
    __shared__ int ls[256];
    int b = blockIdx.x, t = threadIdx.x;
    int base = b * 1024;
    int v[4]; int s = 0;
    for (int j = 0; j < 4; j++) {
        int idx = base + t * 4 + j;
        v[j] = (idx < N) ? cnt[idx] : 0;
        s += v[j];
    }
    ls[t] = s; __syncthreads();
    for (int off = 1; off < 256; off <<= 1) {
        int x = (t >= off) ? ls[t - off] : 0;
        __syncthreads();
        ls[t] += x;
        __syncthreads();
    }
    int excl = ((t == 0) ? 0 : ls[t - 1]) + bsum[b];
    for (int j = 0; j < 4; j++) {
        int idx = base + t * 4 + j;
        if (idx < N) { offs[idx] = excl; cur[idx] = excl; }
        excl += v[j];
        if (idx == N - 1) offs[N] = excl;
    }
}

__global__ __launch_bounds__(256) void k_unbin(const int2* __restrict__ stag,
        const int* __restrict__ bfill, const float* __restrict__ dis,
        int* __restrict__ cur, int2* __restrict__ csr) {
    int b = blockIdx.x & (NBIN - 1);
    int part = blockIdx.x >> 8;          // 0..3 (XCD-aligned: b, b+256, ... same XCD)
    int n = bfill[b];
    const int2* sbase = stag + (size_t)b * SLOT;
    for (int i = part * 256 + threadIdx.x; i < n; i += 1024) {
        int2 rc = sbase[i];
        float v = dis[rc.x] * dis[rc.y];
        int pos = atomicAdd(&cur[rc.y], 1);
        csr[pos] = make_int2(rc.x, __float_as_int(v));
    }
}

// ---------------- combine GEMM (round-8 verified) ----------------

__global__ __launch_bounds__(512, 2) void k_combine_mfma(const ushort* __restrict__ g_bf,
        const ushort* __restrict__ x0_bf, const ushort* __restrict__ wb,
        ushort* __restrict__ h_bf, float* __restrict__ sr) {
    __shared__ uint4 Bl[4096];   // 64 KB
    __shared__ float red1[512];
    __shared__ float red2[512];
    int t = threadIdx.x;
    #pragma unroll
    for (int it = 0; it < 8; it++) {
        int d = it * 512 + t, c = d >> 5, ck = d & 31;
        Bl[c * 32 + (ck ^ (c & 7))] = ((const uint4*)wb)[d];
    }
    __syncthreads();

    int wv = t >> 6, lane = t & 63;
    int l16 = lane & 15, g16 = lane >> 4;
    int row0 = (blockIdx.x * 8 + wv) * 16;
    bool active = row0 < N;

    f32x4 acc[8];
    #pragma unroll
    for (int n = 0; n < 8; n++) acc[n] = f32x4{0.f, 0.f, 0.f, 0.f};

    if (active) {
        const uint4* ga = (const uint4*)(g_bf  + (size_t)(row0 + l16) * 128);
        const uint4* xa = (const uint4*)(x0_bf + (size_t)(row0 + l16) * 128);
        uint4 ar[8];
        #pragma unroll
        for (int ks = 0; ks < 4; ks++) ar[ks]     = ga[ks * 4 + g16];
        #pragma unroll
        for (int ks = 0; ks < 4; ks++) ar[ks + 4] = xa[ks * 4 + g16];

        #pragma unroll
        for (int ks = 0; ks < 8; ks++) {
            bf16x8 a = *(bf16x8*)&ar[ks];
            int xo = (ks * 4 + g16) ^ (l16 & 7);
            const char* bp = (const char*)Bl + l16 * 512 + xo * 16;
            #pragma unroll
            for (int n = 0; n < 8; n++) {
                bf16x8 b = *(const bf16x8*)(bp + n * 8192);
                acc[n] = __builtin_amdgcn_mfma_f32_16x16x32_bf16(a, b, acc[n], 0, 0, 0);
            }
        }
    }

    float sum = 0.f, sq = 0.f;
    if (active) {
        #pragma unroll
        for (int n = 0; n < 8; n++)
            #pragma unroll
            for (int j = 0; j < 4; j++) { float v = acc[n][j]; sum += v; sq += v * v; }
        #pragma unroll
        for (int j = 0; j < 4; j++) {
            int gr = row0 + g16 * 4 + j;
            #pragma unroll
            for (int n = 0; n < 8; n++)
                h_bf[(size_t)gr * 128 + n * 16 + l16] = f2b(acc[n][j]);
        }
    }

    red1[t] = sum; red2[t] = sq; __syncthreads();
    for (int off = 256; off > 0; off >>= 1) {
        if (t < off) { red1[t] += red1[t + off]; red2[t] += red2[t + off]; }
        __syncthreads();
    }
    if (t == 0) { atomicAdd(&sr[0], red1[0]); atomicAdd(&sr[1], red2[0]); }
}

// ---------------- aggregation (verified floor) ----------------

template <int AFFINE>
__global__ __launch_bounds__(256) void k_agg(const ushort* __restrict__ src,
        const int* __restrict__ offs, const int2* __restrict__ csr,
        const float* __restrict__ dis, const float* __restrict__ sr,
        const float* __restrict__ nw, const float* __restrict__ nb,
        ushort* __restrict__ g_bf) {
    int node = blockIdx.x * 4 + (threadIdx.x >> 6);
    if (node >= N) return;
    int lane = threadIdx.x & 63;
    int q = lane >> 4, cl = lane & 15;       // lane owns channels [cl*8, cl*8+8)
    const uint4* fu = (const uint4*)src;     // row = 16 uint4

    f32x2 sc[4], sh[4];
    if constexpr (AFFINE) {
        const float inv_n = 1.0f / ((float)N * (float)D);
        float m = sr[0] * inv_n;
        float var = fmaxf(sr[1] * inv_n - m * m, 0.f);
        float inv = 1.0f / (sqrtf(var) + EPS);
        #pragma unroll
        for (int p = 0; p < 4; p++) {
            float w0 = nw[cl * 8 + 2 * p], w1 = nw[cl * 8 + 2 * p + 1];
            sc[p] = f32x2{inv * w0, inv * w1};
            sh[p] = f32x2{nb[cl * 8 + 2 * p]     - m * inv * w0,
                          nb[cl * 8 + 2 * p + 1] - m * inv * w1};
        }
    }

    f32x2 a2[4];
    #pragma unroll
    for (int p = 0; p < 4; p++) a2[p] = f32x2{0.f, 0.f};

    auto acc8 = [&](float val, uint4 rv) {
        uint uu[4] = {rv.x, rv.y, rv.z, rv.w};
        f32x2 v2 = {val, val};
        #pragma unroll
        for (int p = 0; p < 4; p++) {
            f32x2 c;
            c.x = __uint_as_float(uu[p] << 16);
            c.y = __uint_as_float(uu[p] & 0xffff0000u);
            if constexpr (AFFINE) {
                c = __builtin_elementwise_fma(c, sc[p], sh[p]);
                c = __builtin_elementwise_max(c, f32x2{0.f, 0.f});
            }
            a2[p] = __builtin_elementwise_fma(v2, c, a2[p]);
        }
    };

    float dv = dis[node];
    acc8((q == 0) ? dv * dv : 0.f, fu[(size_t)node * 16 + cl]);   // self loop

    int end = offs[node + 1];
    int i = offs[node] + q * 4;              // group q: quad {i..i+3}, stride 16
    if (i < end) {
        int2 rA[4], rB[4];
        uint4 wA[4];
        #pragma unroll
        for (int s = 0; s < 4; s++) rA[s] = csr[min(i + s, end - 1)];
        #pragma unroll
        for (int s = 0; s < 4; s++) wA[s] = fu[(size_t)rA[s].x * 16 + cl];
        #pragma unroll
        for (int s = 0; s < 4; s++) rB[s] = csr[min(i + 16 + s, end - 1)];
        while (i + 16 < end) {
            uint4 wB[4];
            #pragma unroll
            for (int s = 0; s < 4; s++) wB[s] = fu[(size_t)rB[s].x * 16 + cl];
            int2 rC[4];
            #pragma unroll
            for (int s = 0; s < 4; s++) rC[s] = csr[min(i + 32 + s, end - 1)];
            #pragma unroll
            for (int s = 0; s < 4; s++) acc8(__int_as_float(rA[s].y), wA[s]);
            #pragma unroll
            for (int s = 0; s < 4; s++) { rA[s] = rB[s]; wA[s] = wB[s]; rB[s] = rC[s]; }
            i += 16;
        }
        #pragma unroll
        for (int s = 0; s < 4; s++) {
            float v = (i + s < end) ? __int_as_float(rA[s].y) : 0.f;
            acc8(v, wA[s]);
        }
    }

    #pragma unroll
    for (int p = 0; p < 4; p++) {
        a2[p].x += __shfl_xor(a2[p].x, 16, 64);
        a2[p].x += __shfl_xor(a2[p].x, 32, 64);
        a2[p].y += __shfl_xor(a2[p].y, 16, 64);
        a2[p].y += __shfl_xor(a2[p].y, 32, 64);
    }
    if (q == 0) {
        uint4 o;
        o.x = (uint)f2b(0.5f * a2[0].x) | ((uint)f2b(0.5f * a2[0].y) << 16);
        o.y = (uint)f2b(0.5f * a2[1].x) | ((uint)f2b(0.5f * a2[1].y) << 16);
        o.z = (uint)f2b(0.5f * a2[2].x) | ((uint)f2b(0.5f * a2[2].y) << 16);
        o.w = (uint)f2b(0.5f * a2[3].x) | ((uint)f2b(0.5f * a2[3].y) << 16);
        ((uint4*)g_bf)[(size_t)node * 16 + cl] = o;
    }
}

// ---------------- final LN + relu -> fp32 out ----------------

__global__ void k_ln_final(const ushort* __restrict__ ob, const float* __restrict__ sr,
                           const float* __restrict__ nw, const float* __restrict__ nb,
                           float* __restrict__ fout) {
    int i = blockIdx.x * 256 + threadIdx.x;   // uint4 index: 8 bf16
    if (i >= N * 16) return;
    const float inv_n = 1.0f / ((float)N * (float)D);
    float m = sr[0] * inv_n;
    float var = fmaxf(sr[1] * inv_n - m * m, 0.f);
    float inv = 1.0f / (sqrtf(var) + EPS);
    uint4 v = ((const uint4*)ob)[i];
    int c = (i & 15) * 8;
    uint vv[4] = {v.x, v.y, v.z, v.w};
    float r[8];
    #pragma unroll
    for (int qd = 0; qd < 4; qd++) {
        float lo = b2f((ushort)(vv[qd] & 0xffff));
        float hi = b2f((ushort)(vv[qd] >> 16));
        r[2 * qd]     = fmaxf((lo - m) * inv * nw[c + 2 * qd]     + nb[c + 2 * qd], 0.f);
        r[2 * qd + 1] = fmaxf((hi - m) * inv * nw[c + 2 * qd + 1] + nb[c + 2 * qd + 1], 0.f);
    }
    float4 o0 = {r[0], r[1], r[2], r[3]};
    float4 o1 = {r[4], r[5], r[6], r[7]};
    ((float4*)fout)[2 * i] = o0;
    ((float4*)fout)[2 * i + 1] = o1;
}

// ---------------- launcher ----------------

extern "C" void kernel_launch(void* const* d_in, const int* in_sizes, int n_in,
                              void* d_out, int out_size, void* d_ws, size_t ws_size,
                              hipStream_t stream) {
    const float* x      = (const float*)d_in[0];
    const int*   ei     = (const int*)d_in[1];
    const float* lin1_w = (const float*)d_in[2];
    const float* lin1_b = (const float*)d_in[3];
    const float* w1     = (const float*)d_in[4];
    const float* w2     = (const float*)d_in[5];
    const float* nw     = (const float*)d_in[6];
    const float* nb     = (const float*)d_in[7];
    const int* row = ei;
    const int* col = ei + E;
    float* fout = (float*)d_out;

    char* ws = (char*)d_ws;
    size_t off0 = 0;
    auto alloc = [&](size_t bytes) -> char* {
        char* p = ws + off0;
        off0 = (off0 + bytes + 255) & ~(size_t)255;
        return p;
    };
    ushort* f_bf    = (ushort*)alloc((size_t)N * D * 2);   // f0 (post-relu, layer-0 gather src)
    ushort* x0_bf   = (ushort*)alloc((size_t)N * D * 2);   // 0.5*f0
    ushort* g_bf    = (ushort*)alloc((size_t)N * D * 2);   // agg output
    ushort* h_bf    = (ushort*)alloc((size_t)N * D * 2);   // combine output (pre-LN)
    float*  dis     = (float*) alloc((size_t)N * 4);
    // zero-initialized block: cnt | bfill | stats  (single memset)
    char*   zblk    = alloc((size_t)N * 4 + NBIN * 4 + 64);
    int*    cnt     = (int*)zblk;
    int*    bfill   = (int*)(zblk + (size_t)N * 4);
    float*  stats   = (float*)(zblk + (size_t)N * 4 + NBIN * 4);
    int*    offs    = (int*)   alloc((size_t)(N + 1) * 4);
    int*    cur     = (int*)   alloc((size_t)N * 4);
    int*    bsum    = (int*)   alloc((size_t)128 * 4);
    int2*   stag    = (int2*)  alloc((size_t)NBIN * SLOT * 8);
    int2*   csr     = (int2*)  alloc((size_t)E * 8);
    ushort* wbc     = (ushort*)alloc((size_t)L * D * 256 * 2);

    hipMemsetAsync(zblk, 0, (size_t)N * 4 + NBIN * 4 + 64, stream);

    float4 betas;
    betas.x = logf(1.0f / 1.0f + 1.0f);
    betas.y = logf(1.0f / 2.0f + 1.0f);
    betas.z = logf(1.0f / 3.0f + 1.0f);
    betas.w = logf(1.0f / 4.0f + 1.0f);

    // fused: f0 GEMM (even blocks) | edge count+bin (odd blocks) | wbc prep (tail)
    k_f0_countbin<<<F0B + CBB + PREPB, 512, 0, stream>>>(
        x, lin1_w, lin1_b, f_bf, x0_bf, row, col, cnt, bfill, stag,
        w1, w2, betas, wbc);

    // CSR finish: sum+dis -> scan -> offsets(+cur) -> unbin
    int nbk = (N + 1023) / 1024;   // 98
    k_sumdis<<<nbk, 256, 0, stream>>>(cnt, bsum, dis);
    k_scan<<<1, 128, 0, stream>>>(bsum, nbk);
    k_offsets<<<nbk, 256, 0, stream>>>(cnt, bsum, offs, cur);
    k_unbin<<<NBIN * 4, 256, 0, stream>>>(stag, bfill, dis, cur, csr);

    int GB = (N / 16 + 7) / 8;   // 782
    int AGB = (N + 3) / 4;
    for (int i = 0; i < L; i++) {
        if (i == 0)
            k_agg<0><<<AGB, 256, 0, stream>>>(f_bf, offs, csr, dis, nullptr, nw, nb, g_bf);
        else
            k_agg<1><<<AGB, 256, 0, stream>>>(h_bf, offs, csr, dis, stats + 2 * (i - 1),
                                              nw, nb, g_bf);
        k_combine_mfma<<<GB, 512, 0, stream>>>(g_bf, x0_bf, wbc + (size_t)i * D * 256,
                                               h_bf, stats + 2 * i);
    }
    k_ln_final<<<(N * 16 + 255) / 256, 256, 0, stream>>>(h_bf, stats + 6, nw, nb, fout);
}